// Round 4
// baseline (818.173 us; speedup 1.0000x reference)
//
#include <hip/hip_runtime.h>
#include <hip/hip_bf16.h>

#define N_UNIQ 20000
#define K_NBR 32
#define BATCH 40000
// Inputs fp32, output fp32. Internal: F bf16 [N_UNIQ][384] (agg out, gemm1
// rewrites in place), G fp32 [N_UNIQ][384], packed weight frags wp1/wp2.
// Optional (if ws permits): FB bf16 [V][128] shadow feature table (256 MB,
// fits L3) -> agg random reads hit Infinity Cache at half the bytes.

typedef unsigned short ushort_t;
typedef __bf16 bfrag __attribute__((ext_vector_type(8)));   // 8 bf16 = 4 VGPRs (MFMA A/B)
typedef float  ffrag __attribute__((ext_vector_type(4)));   // MFMA C/D
typedef unsigned uvec4 __attribute__((ext_vector_type(4))); // 16B vector ld/st
typedef unsigned uvec2 __attribute__((ext_vector_type(2)));

__device__ __forceinline__ ushort_t f2bf(float f) {
    unsigned u = __builtin_bit_cast(unsigned, f);
    unsigned r = u + 0x7fffu + ((u >> 16) & 1u);   // round-to-nearest-even
    return (ushort_t)(r >> 16);
}
__device__ __forceinline__ unsigned pack2(float x, float y) {
    return (unsigned)f2bf(x) | ((unsigned)f2bf(y) << 16);
}
// RNE fp32->bf16 on raw bit patterns, two at a time
__device__ __forceinline__ unsigned bfpack_bits(unsigned ux, unsigned uy) {
    unsigned rx = ux + 0x7fffu + ((ux >> 16) & 1u);
    unsigned ry = uy + 0x7fffu + ((uy >> 16) & 1u);
    return (rx >> 16) | (ry & 0xffff0000u);
}
__device__ __forceinline__ float bf2f(unsigned hi16) {   // hi16 in low bits
    return __builtin_bit_cast(float, hi16 << 16);
}

// ---------------------------------------------------------------------------
// Path A prep: fused pack (blocks 0..95) + fp32->bf16 table conversion
// (blocks 96.., grid-stride over 32M uint4s = 128M floats).
// Nontemporal LOADS: don't let the 512 MB fp32 stream evict the FB we write.
// ---------------------------------------------------------------------------
__global__ void conv_pack_kernel(const float* __restrict__ Ws,
                                 const float* __restrict__ Wa,
                                 const float* __restrict__ Wd,
                                 const float* __restrict__ WC,
                                 uint4* __restrict__ wp1,
                                 uint4* __restrict__ wp2,
                                 const float* __restrict__ feat,
                                 uvec2* __restrict__ FB2) {
    if (blockIdx.x < 96) {
        int t = blockIdx.x * blockDim.x + threadIdx.x;   // 0 .. 24575
        int l = t & 63, q = l >> 4, m = l & 15;
        ushort_t v[8];
        if (t < 6144) {                 // 3 * 8nt * 4kk * 64
            int g   = t >> 11;
            int rem = t & 2047;
            int nt  = rem >> 8;
            int kk  = (rem >> 6) & 3;
            const float* W = (g == 0) ? Ws : ((g == 1) ? Wa : Wd);
#pragma unroll
            for (int j = 0; j < 8; j++)
                v[j] = f2bf(W[(kk * 32 + q * 8 + j) * 128 + nt * 16 + m]);
            uint4 u; __builtin_memcpy(&u, v, 16);
            wp1[t] = u;
        } else {
            int t2 = t - 6144;          // 24nt * 12kk * 64
            int nt = t2 / 768;
            int kk = (t2 >> 6) % 12;
#pragma unroll
            for (int j = 0; j < 8; j++)
                v[j] = f2bf(WC[(kk * 32 + q * 8 + j) * 384 + nt * 16 + m]);
            uint4 u; __builtin_memcpy(&u, v, 16);
            wp2[t2] = u;
        }
        return;
    }
    // conversion: one uint4 (4 fp32) -> one uvec2 (4 bf16) per iter
    const uvec4* __restrict__ f4 = (const uvec4*)feat;
    const int total = 1000000 * 128 / 4;               // 32,000,000
    int stride = (gridDim.x - 96) * blockDim.x;
    for (int i = (blockIdx.x - 96) * blockDim.x + threadIdx.x; i < total; i += stride) {
        uvec4 u = __builtin_nontemporal_load(&f4[i]);
        uvec2 p;
        p[0] = bfpack_bits(u[0], u[1]);
        p[1] = bfpack_bits(u[2], u[3]);
        FB2[i] = p;
    }
}

// ---------------------------------------------------------------------------
// Path A agg: one wave per node, reads bf16 rows (256 B) from FB.
// 32 lanes x 8 B = one row per half-wave load; lanes 0-31 adj, 32-63 dis.
// Lane lm covers cols lm*4..lm*4+3 (same mapping as fp32 path).
// Self row is a direct bf16 copy (FB built with the same RNE f2bf).
// ---------------------------------------------------------------------------
__global__ void agg_bf16_kernel(const int* __restrict__ uniq,
                                const int* __restrict__ adjn,
                                const int* __restrict__ disn,
                                const uvec2* __restrict__ FB2,
                                ushort_t* __restrict__ F) {
    int node = (blockIdx.x << 2) + (threadIdx.x >> 6);
    node = __builtin_amdgcn_readfirstlane(node);   // SGPR -> s_load indices
    if (node >= N_UNIQ) return;

    const int l   = threadIdx.x & 63;
    const int lm  = l & 31;
    const bool isdis = (l >= 32);

    const int* __restrict__ na = adjn + node * K_NBR;   // wave-uniform base
    const int* __restrict__ nd = disn + node * K_NBR;

    float ax = 0.f, ay = 0.f, az = 0.f, aw = 0.f;
#pragma unroll
    for (int i = 0; i < K_NBR; i++) {
        int ra = na[i];                    // scalar load
        int rd = nd[i];                    // scalar load
        int r  = isdis ? rd : ra;
        uvec2 v = FB2[r * 32 + lm];        // 8 B/lane: 2 full rows per wave instr
        ax += bf2f(v[0] & 0xffffu);
        ay += bf2f(v[0] >> 16);
        az += bf2f(v[1] & 0xffffu);
        aw += bf2f(v[1] >> 16);
    }

    const float inv = 1.0f / 32.0f;
    ushort_t* row = F + (size_t)node * 384;

    uint2 mpk;
    mpk.x = pack2(ax * inv, ay * inv);
    mpk.y = pack2(az * inv, aw * inv);
    *(uint2*)(row + 128 + (isdis ? 128 : 0) + lm * 4) = mpk;

    if (!isdis) {
        int rs = uniq[node];               // scalar load
        uvec2 sv = FB2[rs * 32 + lm];      // direct bf16 copy, bit-identical
        *(uvec2*)(row + lm * 4) = sv;
    }
}

// ---------------------------------------------------------------------------
// Path B (fallback, byte-identical to round-3): fused pack + fp32 agg.
// ---------------------------------------------------------------------------
__global__ void pack_agg_kernel(const float* __restrict__ Ws,
                                const float* __restrict__ Wa,
                                const float* __restrict__ Wd,
                                const float* __restrict__ WC,
                                uint4* __restrict__ wp1,
                                uint4* __restrict__ wp2,
                                const int* __restrict__ uniq,
                                const int* __restrict__ adjn,
                                const int* __restrict__ disn,
                                const float* __restrict__ feat,
                                ushort_t* __restrict__ F) {
    if (blockIdx.x < 96) {
        int t = blockIdx.x * blockDim.x + threadIdx.x;   // 0 .. 24575
        int l = t & 63, q = l >> 4, m = l & 15;
        ushort_t v[8];
        if (t < 6144) {
            int g   = t >> 11;
            int rem = t & 2047;
            int nt  = rem >> 8;
            int kk  = (rem >> 6) & 3;
            const float* W = (g == 0) ? Ws : ((g == 1) ? Wa : Wd);
#pragma unroll
            for (int j = 0; j < 8; j++)
                v[j] = f2bf(W[(kk * 32 + q * 8 + j) * 128 + nt * 16 + m]);
            uint4 u; __builtin_memcpy(&u, v, 16);
            wp1[t] = u;
        } else {
            int t2 = t - 6144;
            int nt = t2 / 768;
            int kk = (t2 >> 6) % 12;
#pragma unroll
            for (int j = 0; j < 8; j++)
                v[j] = f2bf(WC[(kk * 32 + q * 8 + j) * 384 + nt * 16 + m]);
            uint4 u; __builtin_memcpy(&u, v, 16);
            wp2[t2] = u;
        }
        return;
    }

    int node = ((blockIdx.x - 96) << 2) + (threadIdx.x >> 6);
    node = __builtin_amdgcn_readfirstlane(node);
    if (node >= N_UNIQ) return;

    const int l   = threadIdx.x & 63;
    const int lm  = l & 31;
    const bool isdis = (l >= 32);

    const int* __restrict__ na = adjn + node * K_NBR;
    const int* __restrict__ nd = disn + node * K_NBR;
    const float4* __restrict__ feat4 = (const float4*)feat;

    float ax = 0.f, ay = 0.f, az = 0.f, aw = 0.f;
#pragma unroll
    for (int i = 0; i < K_NBR; i++) {
        int ra = na[i];
        int rd = nd[i];
        int r  = isdis ? rd : ra;
        int idx = r * 32 + lm;
        float4 v = feat4[idx];
        ax += v.x; ay += v.y; az += v.z; aw += v.w;
    }

    const float inv = 1.0f / 32.0f;
    ushort_t* row = F + (size_t)node * 384;

    uint2 mpk;
    mpk.x = pack2(ax * inv, ay * inv);
    mpk.y = pack2(az * inv, aw * inv);
    *(uint2*)(row + 128 + (isdis ? 128 : 0) + lm * 4) = mpk;

    if (!isdis) {
        int rs = uniq[node];
        float4 sv = feat4[rs * 32 + lm];
        uint2 spk;
        spk.x = pack2(sv.x, sv.y);
        spk.y = pack2(sv.z, sv.w);
        *(uint2*)(row + lm * 4) = spk;
    }
}

// ---------------------------------------------------------------------------
// GEMM1 (in-place on F): Y[r, nt*16:..] = X[r, g*128:..] @ W_g + bias
// 1250 blocks x 4 waves = 5000 waves; col-split inside the block; barrier
// then each wave writes its exclusive 96-col slice in place.
// ---------------------------------------------------------------------------
__global__ void gemm1_kernel(ushort_t* __restrict__ F,
                             const uint4* __restrict__ wp1,
                             const float* __restrict__ bias) {
    int grp = blockIdx.x;
    int w   = threadIdx.x >> 6;
    int l = threadIdx.x & 63, q = l >> 4, m = l & 15;
    int m0 = grp * 16;

    uint4 a[12];
    const ushort_t* xrow = F + (size_t)(m0 + m) * 384;
#pragma unroll
    for (int kk = 0; kk < 12; kk++)
        a[kk] = *(const uint4*)(xrow + kk * 32 + q * 8);

    ushort_t outv[6][4];
    int nts[6];
#pragma unroll
    for (int n = 0; n < 6; n++) {
        const int g = n >> 1;                   // compile-time per unroll pos
        int nt = g * 8 + w * 2 + (n & 1);
        nts[n] = nt;
        ffrag acc = {0.f, 0.f, 0.f, 0.f};
        const uint4* wp = wp1 + (size_t)nt * 4 * 64;
#pragma unroll
        for (int kk = 0; kk < 4; kk++) {
            bfrag bf = __builtin_bit_cast(bfrag, wp[kk * 64 + l]);
            bfrag af = __builtin_bit_cast(bfrag, a[g * 4 + kk]);   // static index
            acc = __builtin_amdgcn_mfma_f32_16x16x32_bf16(af, bf, acc, 0, 0, 0);
        }
        float bv = bias[nt * 16 + m];
#pragma unroll
        for (int r = 0; r < 4; r++) outv[n][r] = f2bf(acc[r] + bv);
    }
    __syncthreads();
#pragma unroll
    for (int n = 0; n < 6; n++) {
        int col = nts[n] * 16 + m;
#pragma unroll
        for (int r = 0; r < 4; r++)
            F[(size_t)(m0 + q * 4 + r) * 384 + col] = outv[n][r];
    }
}

// ---------------------------------------------------------------------------
// GEMM2 (F -> G): G = normalize(leaky(F @ WC + WC_b))
// 1250 blocks x 4 waves; wave = 16 rows x 96 cols; LDS norm-reduce.
// ---------------------------------------------------------------------------
__global__ void gemm2_kernel(const ushort_t* __restrict__ F,
                             const uint4* __restrict__ wp2,
                             const float* __restrict__ wcb,
                             float* __restrict__ G) {
    __shared__ float ssred[4][16];
    int grp = blockIdx.x;
    int w   = threadIdx.x >> 6;
    int nt0 = w * 6;
    int l = threadIdx.x & 63, q = l >> 4, m = l & 15;
    int m0 = grp * 16;

    uint4 a[12];
    const ushort_t* xrow = F + (size_t)(m0 + m) * 384;
#pragma unroll
    for (int kk = 0; kk < 12; kk++)
        a[kk] = *(const uint4*)(xrow + kk * 32 + q * 8);

    float vals[6][4];
    float ss[4] = {0.f, 0.f, 0.f, 0.f};
#pragma unroll
    for (int n = 0; n < 6; n++) {
        int nt = nt0 + n;
        ffrag acc = {0.f, 0.f, 0.f, 0.f};
        const uint4* wp = wp2 + (size_t)nt * 12 * 64;
#pragma unroll
        for (int kk = 0; kk < 12; kk++) {
            bfrag bf = __builtin_bit_cast(bfrag, wp[kk * 64 + l]);
            bfrag af = __builtin_bit_cast(bfrag, a[kk]);
            acc = __builtin_amdgcn_mfma_f32_16x16x32_bf16(af, bf, acc, 0, 0, 0);
        }
        float bv = wcb[nt * 16 + m];
#pragma unroll
        for (int r = 0; r < 4; r++) {
            float v = acc[r] + bv;
            v = (v >= 0.f) ? v : 0.2f * v;      // LeakyReLU(0.2)
            vals[n][r] = v;
            ss[r] += v * v;
        }
    }
#pragma unroll
    for (int r = 0; r < 4; r++) {
        float s = ss[r];
        s += __shfl_xor(s, 1);
        s += __shfl_xor(s, 2);
        s += __shfl_xor(s, 4);
        s += __shfl_xor(s, 8);
        ss[r] = s;
    }
    if (m == 0) {
#pragma unroll
        for (int r = 0; r < 4; r++) ssred[w][q * 4 + r] = ss[r];
    }
    __syncthreads();

    float invn[4];
#pragma unroll
    for (int r = 0; r < 4; r++) {
        int row = q * 4 + r;
        float tot = ssred[0][row] + ssred[1][row] + ssred[2][row] + ssred[3][row];
        invn[r] = 1.0f / fmaxf(sqrtf(tot), 1e-12f);
    }
#pragma unroll
    for (int n = 0; n < 6; n++) {
        int col = (nt0 + n) * 16 + m;
#pragma unroll
        for (int r = 0; r < 4; r++)
            G[(size_t)(m0 + q * 4 + r) * 384 + col] = vals[n][r] * invn[r];
    }
}

// ---------------------------------------------------------------------------
// Output gather (fp32): out[b,:] = G[nodes_idx[b],:]  (96 uint4 per row)
// ---------------------------------------------------------------------------
__global__ void gather_kernel(const int* __restrict__ nidx,
                              const uvec4* __restrict__ G4,
                              uvec4* __restrict__ out4) {
    int t = blockIdx.x * blockDim.x + threadIdx.x;
    if (t >= BATCH * 96) return;
    int b = t / 96, c = t - b * 96;
    int row = nidx[b];
    uvec4 v = G4[(size_t)row * 96 + c];
    __builtin_nontemporal_store(v, &out4[(size_t)b * 96 + c]);
}

extern "C" void kernel_launch(void* const* d_in, const int* in_sizes, int n_in,
                              void* d_out, int out_size, void* d_ws, size_t ws_size,
                              hipStream_t stream) {
    const int*   uniq = (const int*)d_in[0];
    const int*   adjn = (const int*)d_in[1];
    const int*   disn = (const int*)d_in[2];
    const int*   nidx = (const int*)d_in[3];
    const float* feat = (const float*)d_in[4];
    const float* Ws   = (const float*)d_in[5];
    const float* Wa   = (const float*)d_in[6];
    const float* Wd   = (const float*)d_in[7];
    const float* bias = (const float*)d_in[8];
    const float* WC   = (const float*)d_in[9];
    const float* wcb  = (const float*)d_in[10];

    ushort_t* F   = (ushort_t*)d_ws;                            // 15,360,000 B (bf16)
    float*    G   = (float*)((char*)d_ws + 15360000);           // 30,720,000 B (fp32)
    uint4*    wp1 = (uint4*)((char*)d_ws + 46080000);           // 98,304 B
    uint4*    wp2 = (uint4*)((char*)d_ws + 46178304);           // 294,912 B
    uvec2*    FB2 = (uvec2*)((char*)d_ws + 46473216);           // 256,000,000 B (bf16 table)
    const size_t NEED_A = 46473216ULL + 256000000ULL;           // 302,473,216 B

    if (ws_size >= NEED_A) {
        // Path A: bf16 shadow table (L3-resident) for the random agg reads
        conv_pack_kernel<<<96 + 4096, 256, 0, stream>>>(
            Ws, Wa, Wd, WC, wp1, wp2, feat, FB2);
        agg_bf16_kernel<<<N_UNIQ / 4, 256, 0, stream>>>(uniq, adjn, disn, FB2, F);
    } else {
        // Path B: round-3-proven fp32 path
        pack_agg_kernel<<<96 + N_UNIQ / 4, 256, 0, stream>>>(
            Ws, Wa, Wd, WC, wp1, wp2, uniq, adjn, disn, feat, F);
    }
    gemm1_kernel<<<N_UNIQ / 16, 256, 0, stream>>>(F, wp1, bias);
    gemm2_kernel<<<N_UNIQ / 16, 256, 0, stream>>>(F, wp2, wcb, G);
    gather_kernel<<<BATCH * 96 / 256, 256, 0, stream>>>(nidx, (const uvec4*)G, (uvec4*)d_out);
}

// Round 5
// 731.006 us; speedup vs baseline: 1.1192x; 1.1192x over previous
//
#include <hip/hip_runtime.h>
#include <hip/hip_bf16.h>

#define N_UNIQ 20000
#define K_NBR 32
#define BATCH 40000
// Inputs fp32, output fp32. Internal: F bf16 [N_UNIQ][384] (agg output),
// G fp32 [N_UNIQ][384] (normalized rows), packed bf16 weight frags wp1/wp2.
// Workspace footprint: 46,473,216 B (r0/r1/r3-proven layout).
// Round-5 structure: pack_agg -> fused(gemm1+LDS-transpose+gemm2) -> gather.

typedef unsigned short ushort_t;
typedef __bf16 bfrag __attribute__((ext_vector_type(8)));   // 8 bf16 = 4 VGPRs (MFMA A/B)
typedef float  ffrag __attribute__((ext_vector_type(4)));   // MFMA C/D
typedef unsigned uvec4 __attribute__((ext_vector_type(4))); // 16B vector ld/st

__device__ __forceinline__ ushort_t f2bf(float f) {
    unsigned u = __builtin_bit_cast(unsigned, f);
    unsigned r = u + 0x7fffu + ((u >> 16) & 1u);   // round-to-nearest-even
    return (ushort_t)(r >> 16);
}
__device__ __forceinline__ unsigned pack2(float x, float y) {
    return (unsigned)f2bf(x) | ((unsigned)f2bf(y) << 16);
}

// ---------------------------------------------------------------------------
// Fused pack (blocks 0..95) + aggregation (blocks 96..).
// Agg is request-bound on random 512B rows (r0->r1 exact null; r4 bf16 table
// net-negative): keep the fp32 direct path.
// ---------------------------------------------------------------------------
__global__ void pack_agg_kernel(const float* __restrict__ Ws,
                                const float* __restrict__ Wa,
                                const float* __restrict__ Wd,
                                const float* __restrict__ WC,
                                uint4* __restrict__ wp1,
                                uint4* __restrict__ wp2,
                                const int* __restrict__ uniq,
                                const int* __restrict__ adjn,
                                const int* __restrict__ disn,
                                const float* __restrict__ feat,
                                ushort_t* __restrict__ F) {
    if (blockIdx.x < 96) {
        // ------------------------- pack path -------------------------
        int t = blockIdx.x * blockDim.x + threadIdx.x;   // 0 .. 24575
        int l = t & 63, q = l >> 4, m = l & 15;
        ushort_t v[8];
        if (t < 6144) {                 // 3 * 8nt * 4kk * 64
            int g   = t >> 11;
            int rem = t & 2047;
            int nt  = rem >> 8;
            int kk  = (rem >> 6) & 3;
            const float* W = (g == 0) ? Ws : ((g == 1) ? Wa : Wd);
#pragma unroll
            for (int j = 0; j < 8; j++)
                v[j] = f2bf(W[(kk * 32 + q * 8 + j) * 128 + nt * 16 + m]);
            uint4 u; __builtin_memcpy(&u, v, 16);
            wp1[t] = u;
        } else {
            int t2 = t - 6144;          // 24nt * 12kk * 64
            int nt = t2 / 768;
            int kk = (t2 >> 6) % 12;
#pragma unroll
            for (int j = 0; j < 8; j++)
                v[j] = f2bf(WC[(kk * 32 + q * 8 + j) * 384 + nt * 16 + m]);
            uint4 u; __builtin_memcpy(&u, v, 16);
            wp2[t2] = u;
        }
        return;
    }

    // ------------------------- agg path -------------------------
    int node = ((blockIdx.x - 96) << 2) + (threadIdx.x >> 6);
    node = __builtin_amdgcn_readfirstlane(node);   // force SGPR -> s_load indices
    if (node >= N_UNIQ) return;

    const int l   = threadIdx.x & 63;
    const int lm  = l & 31;          // float4 slot within the row (32 x 16B = 512B)
    const bool isdis = (l >= 32);    // lanes 0-31: adj rows, lanes 32-63: dis rows

    const int* __restrict__ na = adjn + node * K_NBR;   // wave-uniform base
    const int* __restrict__ nd = disn + node * K_NBR;
    const float4* __restrict__ feat4 = (const float4*)feat;

    float ax = 0.f, ay = 0.f, az = 0.f, aw = 0.f;
#pragma unroll
    for (int i = 0; i < K_NBR; i++) {
        int ra = na[i];                    // scalar load (uniform addr)
        int rd = nd[i];                    // scalar load (uniform addr)
        int r  = isdis ? rd : ra;          // one v_cndmask
        int idx = r * 32 + lm;             // 32-bit voffset, saddr-form load
        float4 v = feat4[idx];             // global_load_dwordx4: 2 rows / wave / instr
        ax += v.x; ay += v.y; az += v.z; aw += v.w;
    }

    const float inv = 1.0f / 32.0f;
    ushort_t* row = F + (size_t)node * 384;

    uint2 mpk;
    mpk.x = pack2(ax * inv, ay * inv);
    mpk.y = pack2(az * inv, aw * inv);
    // adj lanes -> cols [128:256), dis lanes -> cols [256:384)
    *(uint2*)(row + 128 + (isdis ? 128 : 0) + lm * 4) = mpk;

    if (!isdis) {
        // self row: lanes 0-31 fetch 512B, pack to cols [0:128)
        int rs = uniq[node];               // scalar load
        float4 sv = feat4[rs * 32 + lm];
        uint2 spk;
        spk.x = pack2(sv.x, sv.y);
        spk.y = pack2(sv.z, sv.w);
        *(uint2*)(row + lm * 4) = spk;
    }
}

// ---------------------------------------------------------------------------
// Fused GEMM1+GEMM2: one block per 16-row group, 4 waves, col-split.
// Stage 1: Y1 = X @ [Ws|Wa|Wd] + bias, bf16 -> LDS (D-frag layout write).
//   Wave w covers nt = g*8 + w*2 + (n&1), g = n>>1 static (rule #20).
// Barrier. Stage 2: each wave reads its A-frags (row m, 16B contiguous)
// from LDS -- the D-frag->A-frag transpose happens through LDS instead of
// a 30 MB global F round-trip + extra dispatch.
// Stage 2: G = normalize(leaky(Y1 @ WC + wcb)); LDS norm-reduce across waves.
// Numerics identical to the split version: same f2bf rounding point.
// A-frag: A[m=lane&15][k = kk*32 + (lane>>4)*8 + j]
// D-frag: col=lane&15, row=(lane>>4)*4 + r
// ---------------------------------------------------------------------------
#define Y1S 392   // LDS row stride in shorts (16B-aligned; conflicts minor/one-time)
__global__ void gemm_fused_kernel(const ushort_t* __restrict__ F,
                                  const uint4* __restrict__ wp1,
                                  const uint4* __restrict__ wp2,
                                  const float* __restrict__ bias,
                                  const float* __restrict__ wcb,
                                  float* __restrict__ G) {
    __shared__ ushort_t Y1[16][Y1S];
    __shared__ float ssred[4][16];
    int grp = blockIdx.x;                       // 16-row group (0..1249)
    int w   = threadIdx.x >> 6;                 // wave 0..3
    int l = threadIdx.x & 63, q = l >> 4, m = l & 15;
    int m0 = grp * 16;

    // ---- stage 1: Y1 = X @ W_g + bias ----
    uint4 a[12];
    const ushort_t* xrow = F + (size_t)(m0 + m) * 384;
#pragma unroll
    for (int kk = 0; kk < 12; kk++)
        a[kk] = *(const uint4*)(xrow + kk * 32 + q * 8);

#pragma unroll
    for (int n = 0; n < 6; n++) {
        const int g = n >> 1;                   // compile-time per unroll pos
        int nt = g * 8 + w * 2 + (n & 1);
        ffrag acc = {0.f, 0.f, 0.f, 0.f};
        const uint4* wp = wp1 + (size_t)nt * 4 * 64;
#pragma unroll
        for (int kk = 0; kk < 4; kk++) {
            bfrag bf = __builtin_bit_cast(bfrag, wp[kk * 64 + l]);
            bfrag af = __builtin_bit_cast(bfrag, a[g * 4 + kk]);   // static index
            acc = __builtin_amdgcn_mfma_f32_16x16x32_bf16(af, bf, acc, 0, 0, 0);
        }
        float bv = bias[nt * 16 + m];
#pragma unroll
        for (int r = 0; r < 4; r++)
            Y1[q * 4 + r][nt * 16 + m] = f2bf(acc[r] + bv);   // D-frag -> LDS
    }
    __syncthreads();   // full 16x384 Y1 visible to all 4 waves

    // ---- stage 2: out = normalize(leaky(Y1 @ WC + wcb)) ----
    int nt0 = w * 6;
    uint4 a2[12];
#pragma unroll
    for (int kk = 0; kk < 12; kk++)
        a2[kk] = *(const uint4*)(&Y1[m][kk * 32 + q * 8]);    // A-frag from LDS

    float vals[6][4];
    float ss[4] = {0.f, 0.f, 0.f, 0.f};
#pragma unroll
    for (int n = 0; n < 6; n++) {
        int nt = nt0 + n;
        ffrag acc = {0.f, 0.f, 0.f, 0.f};
        const uint4* wp = wp2 + (size_t)nt * 12 * 64;
#pragma unroll
        for (int kk = 0; kk < 12; kk++) {
            bfrag bf = __builtin_bit_cast(bfrag, wp[kk * 64 + l]);
            bfrag af = __builtin_bit_cast(bfrag, a2[kk]);
            acc = __builtin_amdgcn_mfma_f32_16x16x32_bf16(af, bf, acc, 0, 0, 0);
        }
        float bv = wcb[nt * 16 + m];
#pragma unroll
        for (int r = 0; r < 4; r++) {
            float v = acc[r] + bv;
            v = (v >= 0.f) ? v : 0.2f * v;      // LeakyReLU(0.2)
            vals[n][r] = v;
            ss[r] += v * v;
        }
    }
    // partial sum-of-squares over this wave's 96 cols: reduce 16 lanes/quad
#pragma unroll
    for (int r = 0; r < 4; r++) {
        float s = ss[r];
        s += __shfl_xor(s, 1);
        s += __shfl_xor(s, 2);
        s += __shfl_xor(s, 4);
        s += __shfl_xor(s, 8);
        ss[r] = s;
    }
    if (m == 0) {                               // lanes 0,16,32,48
#pragma unroll
        for (int r = 0; r < 4; r++) ssred[w][q * 4 + r] = ss[r];
    }
    __syncthreads();

    float invn[4];
#pragma unroll
    for (int r = 0; r < 4; r++) {
        int row = q * 4 + r;
        float tot = ssred[0][row] + ssred[1][row] + ssred[2][row] + ssred[3][row];
        invn[r] = 1.0f / fmaxf(sqrtf(tot), 1e-12f);
    }
#pragma unroll
    for (int n = 0; n < 6; n++) {
        int col = (nt0 + n) * 16 + m;
#pragma unroll
        for (int r = 0; r < 4; r++)
            G[(size_t)(m0 + q * 4 + r) * 384 + col] = vals[n][r] * invn[r];
    }
}

// ---------------------------------------------------------------------------
// Output gather (fp32): out[b,:] = G[nodes_idx[b],:]  (96 uint4 per row)
// Output is write-once/never-read -> nontemporal stores (keep G cached).
// ---------------------------------------------------------------------------
__global__ void gather_kernel(const int* __restrict__ nidx,
                              const uvec4* __restrict__ G4,
                              uvec4* __restrict__ out4) {
    int t = blockIdx.x * blockDim.x + threadIdx.x;
    if (t >= BATCH * 96) return;
    int b = t / 96, c = t - b * 96;
    int row = nidx[b];
    uvec4 v = G4[(size_t)row * 96 + c];
    __builtin_nontemporal_store(v, &out4[(size_t)b * 96 + c]);
}

extern "C" void kernel_launch(void* const* d_in, const int* in_sizes, int n_in,
                              void* d_out, int out_size, void* d_ws, size_t ws_size,
                              hipStream_t stream) {
    const int*   uniq = (const int*)d_in[0];
    const int*   adjn = (const int*)d_in[1];
    const int*   disn = (const int*)d_in[2];
    const int*   nidx = (const int*)d_in[3];
    const float* feat = (const float*)d_in[4];
    const float* Ws   = (const float*)d_in[5];
    const float* Wa   = (const float*)d_in[6];
    const float* Wd   = (const float*)d_in[7];
    const float* bias = (const float*)d_in[8];
    const float* WC   = (const float*)d_in[9];
    const float* wcb  = (const float*)d_in[10];

    ushort_t* F   = (ushort_t*)d_ws;                            // 15,360,000 B (bf16)
    float*    G   = (float*)((char*)d_ws + 15360000);           // 30,720,000 B (fp32)
    uint4*    wp1 = (uint4*)((char*)d_ws + 46080000);           // 98,304 B
    uint4*    wp2 = (uint4*)((char*)d_ws + 46178304);           // 294,912 B

    pack_agg_kernel<<<96 + N_UNIQ / 4, 256, 0, stream>>>(
        Ws, Wa, Wd, WC, wp1, wp2, uniq, adjn, disn, feat, F);
    gemm_fused_kernel<<<N_UNIQ / 16, 256, 0, stream>>>(F, wp1, wp2, bias, wcb, G);
    gather_kernel<<<BATCH * 96 / 256, 256, 0, stream>>>(nidx, (const uvec4*)G, (uvec4*)d_out);
}